// Round 2
// baseline (388.242 us; speedup 1.0000x reference)
//
#include <hip/hip_runtime.h>
#include <hip/hip_bf16.h>
#include <hip/hip_cooperative_groups.h>

namespace cg = cooperative_groups;

#define IN_DIM 128
#define HC 256
#define HEADS 8
#define OUT_DIM 32
#define NEG_SLOPE 0.2f
#define ELL_CAP 64           // Poisson(16) degrees: P(deg>63) ~ 1e-19 per node

typedef unsigned short ushort_t;
typedef unsigned int uint_t;
typedef __attribute__((ext_vector_type(8))) short bf16x8;
typedef __attribute__((ext_vector_type(8))) unsigned short ushort8_t;
typedef __attribute__((ext_vector_type(4))) float floatx4;

__device__ inline float bf2f(ushort_t u) {
    return __uint_as_float(((uint_t)u) << 16);
}
// packed 2xf32 -> 2xbf16 (v_cvt_pk_bf16_f32), RNE
__device__ inline uint_t pkbf(float a, float b) {
    __hip_bfloat162 t = __float22bfloat162_rn(make_float2(a, b));
    union { __hip_bfloat162 h; uint_t u; } c;
    c.h = t;
    return c.u;
}

struct GatParams {
    const float* x;
    const float* W;
    const float* att_s;
    const float* att_d;
    const float* bias;
    const int* esrc;
    const int* edst;
    float* out;
    ushort_t* h2;
    ushort_t* Wf;
    float* a_src;
    float* a_dst;
    int* deg;
    ushort_t* ell;
    int* ctr;
    int N;
    int E;
};

// One cooperative kernel, three phases split by grid syncs:
//   A: zero deg + pack W->bf16 fragments
//   B: blocks with a GEMM tile do GEMM first; others immediately work-steal
//      ELL-build batches -> atomic drain overlaps MFMA work
//   C: per-wave aggregate (grid-stride over nodes)
__global__ __launch_bounds__(256) void gat_fused(GatParams p) {
    __shared__ ushort_t xs[64 * 136];        // 17408 B -> occupancy not LDS-capped
    const int tid = threadIdx.x;
    const int bid = blockIdx.x;
    const int nb = gridDim.x;
    const int gtid = bid * 256 + tid;
    const int nth = nb * 256;
    const int lane = tid & 63;
    const int w = tid >> 6;

    // ---------------- Phase A ----------------
    for (int i = gtid; i < p.N; i += nth) p.deg[i] = 0;
    if (gtid == 0) *p.ctr = 0;
    if (gtid < 4096) {
        const int t = gtid;
        int l = t & 63;
        int ks = (t >> 6) & 3;
        int nt2 = t >> 8;
        int n = nt2 * 16 + (l & 15);
        int k0 = ks * 32 + (l >> 4) * 8;
        float v[8];
#pragma unroll
        for (int j = 0; j < 8; j++) v[j] = p.W[(size_t)(k0 + j) * HC + n];
        uint4 pk;
        pk.x = pkbf(v[0], v[1]);
        pk.y = pkbf(v[2], v[3]);
        pk.z = pkbf(v[4], v[5]);
        pk.w = pkbf(v[6], v[7]);
        *(uint4*)&p.Wf[(size_t)t * 8] = pk;
    }
    cg::this_grid().sync();

    // ---------------- Phase B ----------------
    // GEMM: 64-row x 256-col tiles; wave w covers cols w*64..w*64+63.
    const int ntiles = (p.N + 63) >> 6;
    const int m15 = lane & 15, quad = lane >> 4;
    const int colblk = w * 64;

    for (int vt = bid; vt < ntiles; vt += nb) {
        const int row0 = vt * 64;
#pragma unroll
        for (int i = 0; i < 8; i++) {
            int slot = tid + i * 256;            // 2048 float4-slots
            int r = slot >> 5, kq = slot & 31;
            int gr = row0 + r;
            float4 v = (gr < p.N) ? *(const float4*)&p.x[(size_t)gr * IN_DIM + kq * 4]
                                  : make_float4(0.f, 0.f, 0.f, 0.f);
            uint2 pk;
            pk.x = pkbf(v.x, v.y);
            pk.y = pkbf(v.z, v.w);
            *(uint2*)&xs[r * 136 + kq * 4] = pk;
        }
        __syncthreads();

        floatx4 acc[4][4] = {};                  // [ct][rt]
#pragma unroll
        for (int ks = 0; ks < 4; ks++) {
            bf16x8 xb[4], wa[4];
#pragma unroll
            for (int rt = 0; rt < 4; rt++)
                xb[rt] = *(const bf16x8*)&xs[(rt * 16 + m15) * 136 + ks * 32 + quad * 8];
#pragma unroll
            for (int ct = 0; ct < 4; ct++) {
                int mtg = (colblk >> 4) + ct;
                wa[ct] = *(const bf16x8*)&p.Wf[(size_t)(((mtg * 4 + ks) * 64) + lane) * 8];
            }
#pragma unroll
            for (int ct = 0; ct < 4; ct++)
#pragma unroll
                for (int rt = 0; rt < 4; rt++)
                    acc[ct][rt] = __builtin_amdgcn_mfma_f32_16x16x32_bf16(wa[ct], xb[rt], acc[ct][rt], 0, 0, 0);
        }

        const int hb = colblk >> 5;              // heads hb, hb+1 in this 64-col span
        float asc[4][4], adc[4][4];
#pragma unroll
        for (int ct = 0; ct < 4; ct++)
#pragma unroll
            for (int reg = 0; reg < 4; reg++) {
                asc[ct][reg] = p.att_s[colblk + ct * 16 + quad * 4 + reg];
                adc[ct][reg] = p.att_d[colblk + ct * 16 + quad * 4 + reg];
            }
#pragma unroll
        for (int rt = 0; rt < 4; rt++) {
            int gr = row0 + rt * 16 + m15;
            bool ok = (gr < p.N);
            if (ok) {
#pragma unroll
                for (int ct = 0; ct < 4; ct++) {
                    uint2 pk;
                    pk.x = pkbf(acc[ct][rt][0], acc[ct][rt][1]);
                    pk.y = pkbf(acc[ct][rt][2], acc[ct][rt][3]);
                    *(uint2*)&p.h2[(size_t)gr * HC + colblk + ct * 16 + quad * 4] = pk;
                }
            }
            float sA = 0.f, sB = 0.f, dA = 0.f, dB = 0.f;
#pragma unroll
            for (int reg = 0; reg < 4; reg++) {
                sA += acc[0][rt][reg] * asc[0][reg] + acc[1][rt][reg] * asc[1][reg];
                sB += acc[2][rt][reg] * asc[2][reg] + acc[3][rt][reg] * asc[3][reg];
                dA += acc[0][rt][reg] * adc[0][reg] + acc[1][rt][reg] * adc[1][reg];
                dB += acc[2][rt][reg] * adc[2][reg] + acc[3][rt][reg] * adc[3][reg];
            }
            sA += __shfl_xor(sA, 16, 64); sA += __shfl_xor(sA, 32, 64);
            sB += __shfl_xor(sB, 16, 64); sB += __shfl_xor(sB, 32, 64);
            dA += __shfl_xor(dA, 16, 64); dA += __shfl_xor(dA, 32, 64);
            dB += __shfl_xor(dB, 16, 64); dB += __shfl_xor(dB, 32, 64);
            if (ok && quad == 0) {
                p.a_src[gr * HEADS + hb]     = sA;
                p.a_src[gr * HEADS + hb + 1] = sB;
                p.a_dst[gr * HEADS + hb]     = dA;
                p.a_dst[gr * HEADS + hb + 1] = dB;
            }
        }
        __syncthreads();
    }

    // ELL build via per-wave work stealing: batch = 64 chunks x 4 edges.
    // Blocks without GEMM tiles reach this at t=0 and absorb the atomic burst
    // while GEMM blocks run MFMA.
    const int nchunk = (p.E + 3) >> 2;
    const int nbatch = (nchunk + 63) >> 6;
    for (;;) {
        int batch = 0;
        if (lane == 0) batch = atomicAdd(p.ctr, 1);
        batch = __shfl(batch, 0, 64);
        if (batch >= nbatch) break;
        int c = batch * 64 + lane;
        if (c < nchunk) {
            int base = c * 4;
            if (base + 3 < p.E) {
                int4 d = *(const int4*)&p.edst[base];
                int4 s = *(const int4*)&p.esrc[base];
                int r0 = atomicAdd(&p.deg[d.x], 1);
                int r1 = atomicAdd(&p.deg[d.y], 1);
                int r2 = atomicAdd(&p.deg[d.z], 1);
                int r3 = atomicAdd(&p.deg[d.w], 1);
                if (r0 < ELL_CAP) p.ell[d.x * ELL_CAP + r0] = (ushort_t)s.x;
                if (r1 < ELL_CAP) p.ell[d.y * ELL_CAP + r1] = (ushort_t)s.y;
                if (r2 < ELL_CAP) p.ell[d.z * ELL_CAP + r2] = (ushort_t)s.z;
                if (r3 < ELL_CAP) p.ell[d.w * ELL_CAP + r3] = (ushort_t)s.w;
            } else {
                for (int j = base; j < p.E; j++) {
                    int r = atomicAdd(&p.deg[p.edst[j]], 1);
                    if (r < ELL_CAP) p.ell[p.edst[j] * ELL_CAP + r] = (ushort_t)p.esrc[j];
                }
            }
        }
    }
    cg::this_grid().sync();

    // ---------------- Phase C: aggregate, one wave per node ----------------
    const int half = lane >> 5;
    const int sl = lane & 31;
    const int head = sl >> 2;
    const int rowoff = sl * 8;                   // ushort offset into 256-elem row
    const int nwv = nb * 4;
    for (int n = bid * 4 + w; n < p.N; n += nwv) {
        float adst = p.a_dst[n * HEADS + head];
        float e = p.a_src[n * HEADS + head] + adst;
        e = fmaxf(e, NEG_SLOPE * e);
        float pp = (half == 0) ? __expf(e) : 0.f;
        ushort8_t hv = *(const ushort8_t*)&p.h2[(size_t)n * HC + rowoff];
        float acc[8];
#pragma unroll
        for (int j = 0; j < 8; j++) acc[j] = pp * bf2f(hv[j]);
        float l = pp;

        int dn = __builtin_amdgcn_readfirstlane(p.deg[n]);
        if (dn > ELL_CAP) dn = ELL_CAP;
        const ushort_t* row = &p.ell[(size_t)n * ELL_CAP];
        int k = 0;
        for (; k + 7 < dn; k += 8) {              // 4 pairs = 8 edges per iter
            int sidx[4];
            float ev[4];
            ushort8_t g[4];
#pragma unroll
            for (int j = 0; j < 4; j++) sidx[j] = (int)row[k + 2 * j + half];
#pragma unroll
            for (int j = 0; j < 4; j++) {
                g[j] = *(const ushort8_t*)&p.h2[(size_t)sidx[j] * HC + rowoff];
                ev[j] = p.a_src[sidx[j] * HEADS + head];
            }
#pragma unroll
            for (int j = 0; j < 4; j++) {
                float ej = ev[j] + adst;
                ej = fmaxf(ej, NEG_SLOPE * ej);
                float pj = __expf(ej);
#pragma unroll
                for (int c = 0; c < 8; c++) acc[c] += pj * bf2f(g[j][c]);
                l += pj;
            }
        }
        for (; k + 1 < dn; k += 2) {              // pair loop
            int s0 = (int)row[k + half];
            float e0 = p.a_src[s0 * HEADS + head] + adst;
            ushort8_t g0 = *(const ushort8_t*)&p.h2[(size_t)s0 * HC + rowoff];
            e0 = fmaxf(e0, NEG_SLOPE * e0);
            float p0 = __expf(e0);
#pragma unroll
            for (int c = 0; c < 8; c++) acc[c] += p0 * bf2f(g0[c]);
            l += p0;
        }
        if (k < dn) {                             // odd tail: half 0 only
            int s0 = (int)row[k];
            float e0 = p.a_src[s0 * HEADS + head] + adst;
            ushort8_t g0 = *(const ushort8_t*)&p.h2[(size_t)s0 * HC + rowoff];
            e0 = fmaxf(e0, NEG_SLOPE * e0);
            float p0 = (half == 0) ? __expf(e0) : 0.f;
#pragma unroll
            for (int c = 0; c < 8; c++) acc[c] += p0 * bf2f(g0[c]);
            l += p0;
        }

#pragma unroll
        for (int j = 0; j < 8; j++) acc[j] += __shfl_xor(acc[j], 32, 64);
        l += __shfl_xor(l, 32, 64);

        float inv = 0.125f / l;                   // fold head-mean 1/8 into normalize
#pragma unroll
        for (int j = 0; j < 8; j++) acc[j] *= inv;
#pragma unroll
        for (int off = 4; off < 32; off <<= 1)
#pragma unroll
            for (int j = 0; j < 8; j++) acc[j] += __shfl_xor(acc[j], off, 64);

        if (lane < 4) {                           // half 0, head 0
            int c8 = sl * 8;
            float4 b0 = *(const float4*)&p.bias[c8];
            float4 b1 = *(const float4*)&p.bias[c8 + 4];
            float4 o0 = make_float4(acc[0] + b0.x, acc[1] + b0.y, acc[2] + b0.z, acc[3] + b0.w);
            float4 o1 = make_float4(acc[4] + b1.x, acc[5] + b1.y, acc[6] + b1.z, acc[7] + b1.w);
            *(float4*)&p.out[(size_t)n * OUT_DIM + c8] = o0;
            *(float4*)&p.out[(size_t)n * OUT_DIM + c8 + 4] = o1;
        }
    }
}

// ---------------- launch ----------------
extern "C" void kernel_launch(void* const* d_in, const int* in_sizes, int n_in,
                              void* d_out, int out_size, void* d_ws, size_t ws_size,
                              hipStream_t stream) {
    const float* x       = (const float*)d_in[0];
    const int*   eidx    = (const int*)d_in[1];
    const float* W       = (const float*)d_in[3];
    const float* att_src = (const float*)d_in[4];
    const float* att_dst = (const float*)d_in[5];
    const float* bias    = (const float*)d_in[6];
    float* out = (float*)d_out;

    const int N = in_sizes[0] / IN_DIM;
    const int E = in_sizes[1] / 2;
    const int* esrc = eidx;
    const int* edst = eidx + E;

    char* wsb = (char*)d_ws;
    size_t off = 0;
    auto alloc = [&](size_t bytes) -> void* {
        void* p = wsb + off;
        off = (off + bytes + 255) & ~(size_t)255;
        return p;
    };
    ushort_t* h2   = (ushort_t*)alloc((size_t)N * HC * 2);
    ushort_t* Wf   = (ushort_t*)alloc((size_t)IN_DIM * HC * 2);
    float*    a_src= (float*)alloc((size_t)N * HEADS * 4);
    float*    a_dst= (float*)alloc((size_t)N * HEADS * 4);
    int*      deg  = (int*)alloc((size_t)N * 4);
    ushort_t* ell  = (ushort_t*)alloc((size_t)N * ELL_CAP * 2);
    int*      ctr  = (int*)alloc(256);

    GatParams hp;
    hp.x = x; hp.W = W; hp.att_s = att_src; hp.att_d = att_dst; hp.bias = bias;
    hp.esrc = esrc; hp.edst = edst; hp.out = out;
    hp.h2 = h2; hp.Wf = Wf; hp.a_src = a_src; hp.a_dst = a_dst;
    hp.deg = deg; hp.ell = ell; hp.ctr = ctr;
    hp.N = N; hp.E = E;

    // Cooperative grid must be <= co-resident capacity; query once.
    static int gridBlocks = 0;
    if (gridBlocks == 0) {
        int maxB = 0;
        if (hipOccupancyMaxActiveBlocksPerMultiprocessor(&maxB, gat_fused, 256, 0) != hipSuccess || maxB < 1)
            maxB = 4;  // conservative fallback (17 KB LDS, <=128 VGPR)
        int dev = 0;
        hipGetDevice(&dev);
        int cus = 0;
        if (hipDeviceGetAttribute(&cus, hipDeviceAttributeMultiprocessorCount, dev) != hipSuccess || cus < 1)
            cus = 256;
        gridBlocks = maxB * cus;
        if (gridBlocks > 4096) gridBlocks = 4096;
    }

    void* args[] = { (void*)&hp };
    hipLaunchCooperativeKernel(gat_fused, dim3(gridBlocks), dim3(256), args, 0, stream);
}

// Round 3
// 282.302 us; speedup vs baseline: 1.3753x; 1.3753x over previous
//
#include <hip/hip_runtime.h>
#include <hip/hip_bf16.h>

#define IN_DIM 128
#define HC 256
#define HEADS 8
#define OUT_DIM 32
#define NEG_SLOPE 0.2f
#define ELL_CAP 64           // Poisson(16) degrees: P(deg>63) ~ 1e-19 per node

typedef unsigned short ushort_t;
typedef unsigned int uint_t;
typedef __attribute__((ext_vector_type(8))) short bf16x8;
typedef __attribute__((ext_vector_type(8))) unsigned short ushort8_t;
typedef __attribute__((ext_vector_type(4))) float floatx4;

__device__ inline float bf2f(ushort_t u) {
    return __uint_as_float(((uint_t)u) << 16);
}
// packed 2xf32 -> 2xbf16 (v_cvt_pk_bf16_f32), RNE
__device__ inline uint_t pkbf(float a, float b) {
    __hip_bfloat162 t = __float22bfloat162_rn(make_float2(a, b));
    union { __hip_bfloat162 h; uint_t u; } c;
    c.h = t;
    return c.u;
}

// ---------------- K1: W -> bf16 swizzled fragments, + zero deg + ctr ----------------
__global__ __launch_bounds__(256) void prep_w_zero(const float* __restrict__ W,
                                                   ushort_t* __restrict__ Wf,
                                                   int* __restrict__ deg,
                                                   int* __restrict__ ctr, int N) {
    const int t = blockIdx.x * 256 + threadIdx.x;     // 0..4095
    for (int i = t; i < N; i += 4096) deg[i] = 0;     // replaces hipMemsetAsync
    if (t == 0) *ctr = 0;

    int lane = t & 63;
    int ks = (t >> 6) & 3;
    int nt2 = t >> 8;
    int n = nt2 * 16 + (lane & 15);
    int k0 = ks * 32 + (lane >> 4) * 8;
    float v[8];
#pragma unroll
    for (int j = 0; j < 8; j++) v[j] = W[(size_t)(k0 + j) * HC + n];
    uint4 pk;
    pk.x = pkbf(v[0], v[1]);
    pk.y = pkbf(v[2], v[3]);
    pk.z = pkbf(v[4], v[5]);
    pk.w = pkbf(v[6], v[7]);
    *(uint4*)&Wf[(size_t)t * 8] = pk;
}

// ---------------- K2: [GEMM-tile blocks first | pure-build blocks], all steal build ----------------
// GEMM blocks (one 64x256 tile each) come FIRST in block order so the atomic
// drain of the ELL build overlaps the MFMA+stream work: pure-build blocks fill
// the remaining residency at t=0, and GEMM blocks join the steal loop as they
// finish their tile.
__global__ __launch_bounds__(256) void gemm_build(const float* __restrict__ x,
                                                  const ushort_t* __restrict__ Wf,
                                                  const float* __restrict__ att_s,
                                                  const float* __restrict__ att_d,
                                                  ushort_t* __restrict__ h2,
                                                  float* __restrict__ a_src,
                                                  float* __restrict__ a_dst,
                                                  const int* __restrict__ esrc,
                                                  const int* __restrict__ edst,
                                                  int* __restrict__ deg,
                                                  ushort_t* __restrict__ ell,
                                                  int* __restrict__ ctr,
                                                  int N, int E, int ntiles) {
    __shared__ ushort_t xs[64 * 136];        // 17408 B
    const int tid = threadIdx.x;
    const int bid = blockIdx.x;
    const int lane = tid & 63;
    const int w = tid >> 6;

    if (bid < ntiles) {
        // ---- GEMM: 64-row x 256-col tile; wave w covers cols w*64..w*64+63 ----
        const int row0 = bid * 64;
        const int m15 = lane & 15, quad = lane >> 4;
        const int colblk = w * 64;
#pragma unroll
        for (int i = 0; i < 8; i++) {
            int slot = tid + i * 256;            // 2048 float4-slots
            int r = slot >> 5, kq = slot & 31;
            int gr = row0 + r;
            float4 v = (gr < N) ? *(const float4*)&x[(size_t)gr * IN_DIM + kq * 4]
                                : make_float4(0.f, 0.f, 0.f, 0.f);
            uint2 pk;
            pk.x = pkbf(v.x, v.y);
            pk.y = pkbf(v.z, v.w);
            *(uint2*)&xs[r * 136 + kq * 4] = pk;
        }
        __syncthreads();

        floatx4 acc[4][4] = {};                  // [ct][rt]
#pragma unroll
        for (int ks = 0; ks < 4; ks++) {
            bf16x8 xb[4], wa[4];
#pragma unroll
            for (int rt = 0; rt < 4; rt++)
                xb[rt] = *(const bf16x8*)&xs[(rt * 16 + m15) * 136 + ks * 32 + quad * 8];
#pragma unroll
            for (int ct = 0; ct < 4; ct++) {
                int mtg = (colblk >> 4) + ct;
                wa[ct] = *(const bf16x8*)&Wf[(size_t)(((mtg * 4 + ks) * 64) + lane) * 8];
            }
#pragma unroll
            for (int ct = 0; ct < 4; ct++)
#pragma unroll
                for (int rt = 0; rt < 4; rt++)
                    acc[ct][rt] = __builtin_amdgcn_mfma_f32_16x16x32_bf16(wa[ct], xb[rt], acc[ct][rt], 0, 0, 0);
        }

        const int hb = colblk >> 5;              // heads hb, hb+1 in this 64-col span
        float asc[4][4], adc[4][4];
#pragma unroll
        for (int ct = 0; ct < 4; ct++)
#pragma unroll
            for (int reg = 0; reg < 4; reg++) {
                asc[ct][reg] = att_s[colblk + ct * 16 + quad * 4 + reg];
                adc[ct][reg] = att_d[colblk + ct * 16 + quad * 4 + reg];
            }
#pragma unroll
        for (int rt = 0; rt < 4; rt++) {
            int gr = row0 + rt * 16 + m15;
            bool ok = (gr < N);
            if (ok) {
#pragma unroll
                for (int ct = 0; ct < 4; ct++) {
                    uint2 pk;
                    pk.x = pkbf(acc[ct][rt][0], acc[ct][rt][1]);
                    pk.y = pkbf(acc[ct][rt][2], acc[ct][rt][3]);
                    *(uint2*)&h2[(size_t)gr * HC + colblk + ct * 16 + quad * 4] = pk;
                }
            }
            float sA = 0.f, sB = 0.f, dA = 0.f, dB = 0.f;
#pragma unroll
            for (int reg = 0; reg < 4; reg++) {
                sA += acc[0][rt][reg] * asc[0][reg] + acc[1][rt][reg] * asc[1][reg];
                sB += acc[2][rt][reg] * asc[2][reg] + acc[3][rt][reg] * asc[3][reg];
                dA += acc[0][rt][reg] * adc[0][reg] + acc[1][rt][reg] * adc[1][reg];
                dB += acc[2][rt][reg] * adc[2][reg] + acc[3][rt][reg] * adc[3][reg];
            }
            sA += __shfl_xor(sA, 16, 64); sA += __shfl_xor(sA, 32, 64);
            sB += __shfl_xor(sB, 16, 64); sB += __shfl_xor(sB, 32, 64);
            dA += __shfl_xor(dA, 16, 64); dA += __shfl_xor(dA, 32, 64);
            dB += __shfl_xor(dB, 16, 64); dB += __shfl_xor(dB, 32, 64);
            if (ok && quad == 0) {
                a_src[gr * HEADS + hb]     = sA;
                a_src[gr * HEADS + hb + 1] = sB;
                a_dst[gr * HEADS + hb]     = dA;
                a_dst[gr * HEADS + hb + 1] = dB;
            }
        }
    }

    // ---- ELL build via per-wave work stealing: batch = 64 lanes x 8 edges ----
    const int nchunk = (E + 7) >> 3;
    const int nbatch = (nchunk + 63) >> 6;
    for (;;) {
        int batch = 0;
        if (lane == 0) batch = atomicAdd(ctr, 1);
        batch = __shfl(batch, 0, 64);
        if (batch >= nbatch) break;
        int c = batch * 64 + lane;
        if (c < nchunk) {
            int base = c * 8;
            if (base + 7 < E) {
                int4 d0 = *(const int4*)&edst[base];
                int4 d1 = *(const int4*)&edst[base + 4];
                int4 s0 = *(const int4*)&esrc[base];
                int4 s1 = *(const int4*)&esrc[base + 4];
                int r0 = atomicAdd(&deg[d0.x], 1);
                int r1 = atomicAdd(&deg[d0.y], 1);
                int r2 = atomicAdd(&deg[d0.z], 1);
                int r3 = atomicAdd(&deg[d0.w], 1);
                int r4 = atomicAdd(&deg[d1.x], 1);
                int r5 = atomicAdd(&deg[d1.y], 1);
                int r6 = atomicAdd(&deg[d1.z], 1);
                int r7 = atomicAdd(&deg[d1.w], 1);
                if (r0 < ELL_CAP) ell[d0.x * ELL_CAP + r0] = (ushort_t)s0.x;
                if (r1 < ELL_CAP) ell[d0.y * ELL_CAP + r1] = (ushort_t)s0.y;
                if (r2 < ELL_CAP) ell[d0.z * ELL_CAP + r2] = (ushort_t)s0.z;
                if (r3 < ELL_CAP) ell[d0.w * ELL_CAP + r3] = (ushort_t)s0.w;
                if (r4 < ELL_CAP) ell[d1.x * ELL_CAP + r4] = (ushort_t)s1.x;
                if (r5 < ELL_CAP) ell[d1.y * ELL_CAP + r5] = (ushort_t)s1.y;
                if (r6 < ELL_CAP) ell[d1.z * ELL_CAP + r6] = (ushort_t)s1.z;
                if (r7 < ELL_CAP) ell[d1.w * ELL_CAP + r7] = (ushort_t)s1.w;
            } else {
                for (int j = base; j < E; j++) {
                    int r = atomicAdd(&deg[edst[j]], 1);
                    if (r < ELL_CAP) ell[edst[j] * ELL_CAP + r] = (ushort_t)esrc[j];
                }
            }
        }
    }
}

// ---------------- K3: aggregate — one node per HALF-wave, 8 gathers in flight per half ----------------
__global__ __launch_bounds__(256) void aggregate(const ushort_t* __restrict__ h2,
                                                 const float* __restrict__ a_src,
                                                 const float* __restrict__ a_dst,
                                                 const int* __restrict__ deg,
                                                 const ushort_t* __restrict__ ell,
                                                 const float* __restrict__ bias,
                                                 float* __restrict__ out, int N) {
    const int wave = threadIdx.x >> 6;
    const int lane = threadIdx.x & 63;
    const int half = lane >> 5;
    const int sl = lane & 31;
    const int head = sl >> 2;
    const int rowoff = sl * 8;                    // ushort offset into 256-elem row

    const int node = blockIdx.x * 8 + wave * 2 + half;
    const bool nok = (node < N);
    const int nd = nok ? node : 0;

    float adst = a_dst[nd * HEADS + head];
    float e0 = a_src[nd * HEADS + head] + adst;   // self-loop
    e0 = fmaxf(e0, NEG_SLOPE * e0);
    float p = __expf(e0);
    ushort8_t hv = *(const ushort8_t*)&h2[(size_t)nd * HC + rowoff];
    float acc[8];
#pragma unroll
    for (int j = 0; j < 8; j++) acc[j] = p * bf2f(hv[j]);
    float l = p;

    int dn = deg[nd];                             // uniform within half
    if (dn > ELL_CAP) dn = ELL_CAP;
    const ushort_t* row = &ell[(size_t)nd * ELL_CAP];

    for (int k = 0; k < dn; k += 8) {
        int sidx[8];
        float ev[8];
        ushort8_t g[8];
        bool vm[8];
#pragma unroll
        for (int j = 0; j < 8; j++) {
            int kj = k + j;
            vm[j] = (kj < dn);
            int slot = (kj < ELL_CAP) ? kj : (ELL_CAP - 1);   // always in-bounds load
            int s = (int)row[slot];
            sidx[j] = vm[j] ? s : 0;                          // clamp addr for invalid
        }
#pragma unroll
        for (int j = 0; j < 8; j++) {
            g[j] = *(const ushort8_t*)&h2[(size_t)sidx[j] * HC + rowoff];
            ev[j] = a_src[sidx[j] * HEADS + head];
        }
#pragma unroll
        for (int j = 0; j < 8; j++) {
            float ej = ev[j] + adst;
            ej = fmaxf(ej, NEG_SLOPE * ej);
            float pj = vm[j] ? __expf(ej) : 0.f;
#pragma unroll
            for (int c = 0; c < 8; c++) acc[c] += pj * bf2f(g[j][c]);
            l += pj;
        }
    }

    // per-head normalize (l identical across the 8 lanes of a head within this half)
    float inv = 0.125f / l;                       // fold head-mean 1/8
#pragma unroll
    for (int j = 0; j < 8; j++) acc[j] *= inv;
    // head-mean reduce: xor 4/8/16 stays within the 32-lane half
#pragma unroll
    for (int off = 4; off < 32; off <<= 1)
#pragma unroll
        for (int j = 0; j < 8; j++) acc[j] += __shfl_xor(acc[j], off, 64);

    if (nok && sl < 4) {                          // head-0 lanes of each half write their node
        int c8 = sl * 8;
        float4 b0 = *(const float4*)&bias[c8];
        float4 b1 = *(const float4*)&bias[c8 + 4];
        float4 o0 = make_float4(acc[0] + b0.x, acc[1] + b0.y, acc[2] + b0.z, acc[3] + b0.w);
        float4 o1 = make_float4(acc[4] + b1.x, acc[5] + b1.y, acc[6] + b1.z, acc[7] + b1.w);
        *(float4*)&out[(size_t)node * OUT_DIM + c8] = o0;
        *(float4*)&out[(size_t)node * OUT_DIM + c8 + 4] = o1;
    }
}

// ---------------- launch ----------------
extern "C" void kernel_launch(void* const* d_in, const int* in_sizes, int n_in,
                              void* d_out, int out_size, void* d_ws, size_t ws_size,
                              hipStream_t stream) {
    const float* x       = (const float*)d_in[0];
    const int*   eidx    = (const int*)d_in[1];
    const float* W       = (const float*)d_in[3];
    const float* att_src = (const float*)d_in[4];
    const float* att_dst = (const float*)d_in[5];
    const float* bias    = (const float*)d_in[6];
    float* out = (float*)d_out;

    const int N = in_sizes[0] / IN_DIM;
    const int E = in_sizes[1] / 2;
    const int* esrc = eidx;
    const int* edst = eidx + E;

    char* wsb = (char*)d_ws;
    size_t off = 0;
    auto alloc = [&](size_t bytes) -> void* {
        void* p = wsb + off;
        off = (off + bytes + 255) & ~(size_t)255;
        return p;
    };
    ushort_t* h2   = (ushort_t*)alloc((size_t)N * HC * 2);
    ushort_t* Wf   = (ushort_t*)alloc((size_t)IN_DIM * HC * 2);
    float*    a_src= (float*)alloc((size_t)N * HEADS * 4);
    float*    a_dst= (float*)alloc((size_t)N * HEADS * 4);
    int*      deg  = (int*)alloc((size_t)N * 4);
    ushort_t* ell  = (ushort_t*)alloc((size_t)N * ELL_CAP * 2);
    int*      ctr  = (int*)alloc(256);

    const int ntiles = (N + 63) / 64;
    const int nblk2  = ntiles + 512;              // extra pure-build blocks

    hipLaunchKernelGGL(prep_w_zero, dim3(16), dim3(256), 0, stream, W, Wf, deg, ctr, N);
    hipLaunchKernelGGL(gemm_build, dim3(nblk2), dim3(256), 0, stream,
                       x, Wf, att_src, att_dst, h2, a_src, a_dst,
                       esrc, edst, deg, ell, ctr, N, E, ntiles);
    hipLaunchKernelGGL(aggregate, dim3((N + 7) / 8), dim3(256), 0, stream,
                       h2, a_src, a_dst, deg, ell, bias, out, N);
}

// Round 4
// 211.568 us; speedup vs baseline: 1.8351x; 1.3343x over previous
//
#include <hip/hip_runtime.h>
#include <hip/hip_bf16.h>

#define IN_DIM 128
#define HC 256
#define HEADS 8
#define OUT_DIM 32
#define NEG_SLOPE 0.2f
#define ELL_CAP 64           // Poisson(16) degrees: P(deg>63) ~ 1e-19 per node

typedef unsigned short ushort_t;
typedef unsigned int uint_t;
typedef __attribute__((ext_vector_type(8))) short bf16x8;
typedef __attribute__((ext_vector_type(8))) unsigned short ushort8_t;
typedef __attribute__((ext_vector_type(4))) float floatx4;

__device__ inline float bf2f(ushort_t u) {
    return __uint_as_float(((uint_t)u) << 16);
}
// packed 2xf32 -> 2xbf16 (v_cvt_pk_bf16_f32), RNE
__device__ inline uint_t pkbf(float a, float b) {
    __hip_bfloat162 t = __float22bfloat162_rn(make_float2(a, b));
    union { __hip_bfloat162 h; uint_t u; } c;
    c.h = t;
    return c.u;
}

// ---------------- K1: fused [prep_w blocks | ELL-build blocks] ----------------
__global__ __launch_bounds__(256) void prep_build(const float* __restrict__ W,
                                                  ushort_t* __restrict__ Wf,
                                                  const int* __restrict__ esrc,
                                                  const int* __restrict__ edst,
                                                  int* __restrict__ deg,
                                                  ushort_t* __restrict__ ell, int E) {
    const int bid = blockIdx.x;
    const int tid = threadIdx.x;
    if (bid < 16) {
        int t = bid * 256 + tid;                 // 0..4095
        int lane = t & 63;
        int ks = (t >> 6) & 3;
        int nt = t >> 8;
        int n = nt * 16 + (lane & 15);
        int k0 = ks * 32 + (lane >> 4) * 8;
        float v[8];
#pragma unroll
        for (int j = 0; j < 8; j++) v[j] = W[(size_t)(k0 + j) * HC + n];
        uint4 pk;
        pk.x = pkbf(v[0], v[1]);
        pk.y = pkbf(v[2], v[3]);
        pk.z = pkbf(v[4], v[5]);
        pk.w = pkbf(v[6], v[7]);
        *(uint4*)&Wf[(size_t)t * 8] = pk;
        return;
    }
    int i = (bid - 16) * 256 + tid;
    int base = i * 4;
    if (base + 3 < E) {
        int4 d = *(const int4*)&edst[base];
        int4 s = *(const int4*)&esrc[base];
        int r0 = atomicAdd(&deg[d.x], 1);
        int r1 = atomicAdd(&deg[d.y], 1);
        int r2 = atomicAdd(&deg[d.z], 1);
        int r3 = atomicAdd(&deg[d.w], 1);
        if (r0 < ELL_CAP) ell[d.x * ELL_CAP + r0] = (ushort_t)s.x;
        if (r1 < ELL_CAP) ell[d.y * ELL_CAP + r1] = (ushort_t)s.y;
        if (r2 < ELL_CAP) ell[d.z * ELL_CAP + r2] = (ushort_t)s.z;
        if (r3 < ELL_CAP) ell[d.w * ELL_CAP + r3] = (ushort_t)s.w;
    } else {
        for (int j = base; j < E; j++) {
            int r = atomicAdd(&deg[edst[j]], 1);
            if (r < ELL_CAP) ell[edst[j] * ELL_CAP + r] = (ushort_t)esrc[j];
        }
    }
}

// ---------------- K2: h2 = bf16(x @ W) via MFMA, operand-swapped ----------------
__global__ __launch_bounds__(256) void gemm_mfma(const float* __restrict__ x,
                                                 const ushort_t* __restrict__ Wf,
                                                 const float* __restrict__ att_s,
                                                 const float* __restrict__ att_d,
                                                 ushort_t* __restrict__ h2,
                                                 float* __restrict__ a_src,
                                                 float* __restrict__ a_dst, int N) {
    __shared__ ushort_t xs[128 * 136];
    const int tid = threadIdx.x;
    const int row0 = blockIdx.x * 128;
#pragma unroll
    for (int i = 0; i < 16; i++) {
        int slot = tid + i * 256;                // 4096 float4-slots
        int r = slot >> 5, kq = slot & 31;
        int gr = row0 + r;
        float4 v = (gr < N) ? *(const float4*)&x[(size_t)gr * IN_DIM + kq * 4]
                            : make_float4(0.f, 0.f, 0.f, 0.f);
        uint2 pk;
        pk.x = pkbf(v.x, v.y);
        pk.y = pkbf(v.z, v.w);
        *(uint2*)&xs[r * 136 + kq * 4] = pk;
    }
    __syncthreads();

    const int lane = tid & 63;
    const int w = tid >> 6;
    const int wrow = (w & 1) * 64;               // wave row offset
    const int wcol = (w >> 1) * 64;              // wave col offset within 128
    const int m15 = lane & 15, quad = lane >> 4;

#pragma unroll
    for (int ch = 0; ch < 2; ch++) {
        const int colblk = wcol + ch * 128;      // global col base (HC=256)
        floatx4 acc[4][4] = {};                  // [ct][rt]
#pragma unroll
        for (int ks = 0; ks < 4; ks++) {
            bf16x8 xb[4], wa[4];
#pragma unroll
            for (int rt = 0; rt < 4; rt++)
                xb[rt] = *(const bf16x8*)&xs[(wrow + rt * 16 + m15) * 136 + ks * 32 + quad * 8];
#pragma unroll
            for (int ct = 0; ct < 4; ct++) {
                int mtg = (colblk >> 4) + ct;
                wa[ct] = *(const bf16x8*)&Wf[(size_t)(((mtg * 4 + ks) * 64) + lane) * 8];
            }
#pragma unroll
            for (int ct = 0; ct < 4; ct++)
#pragma unroll
                for (int rt = 0; rt < 4; rt++)
                    acc[ct][rt] = __builtin_amdgcn_mfma_f32_16x16x32_bf16(wa[ct], xb[rt], acc[ct][rt], 0, 0, 0);
        }

        const int hb = colblk >> 5;              // heads hb, hb+1 in this 64-col span
        float asc[4][4], adc[4][4];
#pragma unroll
        for (int ct = 0; ct < 4; ct++)
#pragma unroll
            for (int reg = 0; reg < 4; reg++) {
                asc[ct][reg] = att_s[colblk + ct * 16 + quad * 4 + reg];
                adc[ct][reg] = att_d[colblk + ct * 16 + quad * 4 + reg];
            }
#pragma unroll
        for (int rt = 0; rt < 4; rt++) {
            int gr = row0 + wrow + rt * 16 + m15;
            bool ok = (gr < N);
            if (ok) {
#pragma unroll
                for (int ct = 0; ct < 4; ct++) {
                    uint2 pk;
                    pk.x = pkbf(acc[ct][rt][0], acc[ct][rt][1]);
                    pk.y = pkbf(acc[ct][rt][2], acc[ct][rt][3]);
                    *(uint2*)&h2[(size_t)gr * HC + colblk + ct * 16 + quad * 4] = pk;
                }
            }
            float sA = 0.f, sB = 0.f, dA = 0.f, dB = 0.f;
#pragma unroll
            for (int reg = 0; reg < 4; reg++) {
                sA += acc[0][rt][reg] * asc[0][reg] + acc[1][rt][reg] * asc[1][reg];
                sB += acc[2][rt][reg] * asc[2][reg] + acc[3][rt][reg] * asc[3][reg];
                dA += acc[0][rt][reg] * adc[0][reg] + acc[1][rt][reg] * adc[1][reg];
                dB += acc[2][rt][reg] * adc[2][reg] + acc[3][rt][reg] * adc[3][reg];
            }
            sA += __shfl_xor(sA, 16, 64); sA += __shfl_xor(sA, 32, 64);
            sB += __shfl_xor(sB, 16, 64); sB += __shfl_xor(sB, 32, 64);
            dA += __shfl_xor(dA, 16, 64); dA += __shfl_xor(dA, 32, 64);
            dB += __shfl_xor(dB, 16, 64); dB += __shfl_xor(dB, 32, 64);
            if (ok && quad == 0) {
                a_src[gr * HEADS + hb]     = sA;
                a_src[gr * HEADS + hb + 1] = sB;
                a_dst[gr * HEADS + hb]     = dA;
                a_dst[gr * HEADS + hb + 1] = dB;
            }
        }
    }
}

// ---------------- K3: aggregate — one wave per node, 16 edges in flight per wave ----------------
__global__ __launch_bounds__(256) void aggregate(const ushort_t* __restrict__ h2,
                                                 const float* __restrict__ a_src,
                                                 const float* __restrict__ a_dst,
                                                 const int* __restrict__ deg,
                                                 const ushort_t* __restrict__ ell,
                                                 const float* __restrict__ bias,
                                                 float* __restrict__ out, int N) {
    int wave = threadIdx.x >> 6;
    int lane = threadIdx.x & 63;
    int n = blockIdx.x * 4 + wave;
    if (n >= N) return;
    int half = lane >> 5;
    int sl = lane & 31;
    int head = sl >> 2;
    int rowoff = sl * 8;                          // ushort offset into 256-elem row

    float adst = a_dst[n * HEADS + head];
    float e = a_src[n * HEADS + head] + adst;
    e = fmaxf(e, NEG_SLOPE * e);
    float p = (half == 0) ? __expf(e) : 0.f;
    ushort8_t hv = *(const ushort8_t*)&h2[(size_t)n * HC + rowoff];
    float acc[8];
#pragma unroll
    for (int j = 0; j < 8; j++) acc[j] = p * bf2f(hv[j]);
    float l = p;

    int dn = __builtin_amdgcn_readfirstlane(deg[n]);
    if (dn > ELL_CAP) dn = ELL_CAP;
    const ushort_t* row = &ell[(size_t)n * ELL_CAP];
    int k = 0;
    for (; k + 15 < dn; k += 16) {                // 8 pairs = 16 edges per iter (MLP x2)
        int sidx[8];
        float ev[8];
        ushort8_t g[8];
#pragma unroll
        for (int j = 0; j < 8; j++) sidx[j] = (int)row[k + 2 * j + half];
#pragma unroll
        for (int j = 0; j < 8; j++) {
            g[j] = *(const ushort8_t*)&h2[(size_t)sidx[j] * HC + rowoff];
            ev[j] = a_src[sidx[j] * HEADS + head];
        }
#pragma unroll
        for (int j = 0; j < 8; j++) {
            float ej = ev[j] + adst;
            ej = fmaxf(ej, NEG_SLOPE * ej);
            float pj = __expf(ej);
#pragma unroll
            for (int c = 0; c < 8; c++) acc[c] += pj * bf2f(g[j][c]);
            l += pj;
        }
    }
    for (; k + 7 < dn; k += 8) {                  // 4 pairs = 8 edges per iter
        int sidx[4];
        float ev[4];
        ushort8_t g[4];
#pragma unroll
        for (int j = 0; j < 4; j++) sidx[j] = (int)row[k + 2 * j + half];
#pragma unroll
        for (int j = 0; j < 4; j++) {
            g[j] = *(const ushort8_t*)&h2[(size_t)sidx[j] * HC + rowoff];
            ev[j] = a_src[sidx[j] * HEADS + head];
        }
#pragma unroll
        for (int j = 0; j < 4; j++) {
            float ej = ev[j] + adst;
            ej = fmaxf(ej, NEG_SLOPE * ej);
            float pj = __expf(ej);
#pragma unroll
            for (int c = 0; c < 8; c++) acc[c] += pj * bf2f(g[j][c]);
            l += pj;
        }
    }
    for (; k + 1 < dn; k += 2) {                  // pair loop
        int s0 = (int)row[k + half];
        float e0 = a_src[s0 * HEADS + head] + adst;
        ushort8_t g0 = *(const ushort8_t*)&h2[(size_t)s0 * HC + rowoff];
        e0 = fmaxf(e0, NEG_SLOPE * e0);
        float p0 = __expf(e0);
#pragma unroll
        for (int c = 0; c < 8; c++) acc[c] += p0 * bf2f(g0[c]);
        l += p0;
    }
    if (k < dn) {                                 // odd tail: half 0 only
        int s0 = (int)row[k];
        float e0 = a_src[s0 * HEADS + head] + adst;
        ushort8_t g0 = *(const ushort8_t*)&h2[(size_t)s0 * HC + rowoff];
        e0 = fmaxf(e0, NEG_SLOPE * e0);
        float p0 = (half == 0) ? __expf(e0) : 0.f;
#pragma unroll
        for (int c = 0; c < 8; c++) acc[c] += p0 * bf2f(g0[c]);
        l += p0;
    }

#pragma unroll
    for (int j = 0; j < 8; j++) acc[j] += __shfl_xor(acc[j], 32, 64);
    l += __shfl_xor(l, 32, 64);

    float inv = 0.125f / l;                       // fold head-mean 1/8 into normalize
#pragma unroll
    for (int j = 0; j < 8; j++) acc[j] *= inv;
#pragma unroll
    for (int off = 4; off < 32; off <<= 1)
#pragma unroll
        for (int j = 0; j < 8; j++) acc[j] += __shfl_xor(acc[j], off, 64);

    if (lane < 4) {                               // half 0, head 0
        int c8 = sl * 8;
        float4 b0 = *(const float4*)&bias[c8];
        float4 b1 = *(const float4*)&bias[c8 + 4];
        float4 o0 = make_float4(acc[0] + b0.x, acc[1] + b0.y, acc[2] + b0.z, acc[3] + b0.w);
        float4 o1 = make_float4(acc[4] + b1.x, acc[5] + b1.y, acc[6] + b1.z, acc[7] + b1.w);
        *(float4*)&out[(size_t)n * OUT_DIM + c8] = o0;
        *(float4*)&out[(size_t)n * OUT_DIM + c8 + 4] = o1;
    }
}

// ---------------- launch ----------------
extern "C" void kernel_launch(void* const* d_in, const int* in_sizes, int n_in,
                              void* d_out, int out_size, void* d_ws, size_t ws_size,
                              hipStream_t stream) {
    const float* x       = (const float*)d_in[0];
    const int*   eidx    = (const int*)d_in[1];
    const float* W       = (const float*)d_in[3];
    const float* att_src = (const float*)d_in[4];
    const float* att_dst = (const float*)d_in[5];
    const float* bias    = (const float*)d_in[6];
    float* out = (float*)d_out;

    const int N = in_sizes[0] / IN_DIM;
    const int E = in_sizes[1] / 2;
    const int* esrc = eidx;
    const int* edst = eidx + E;

    char* wsb = (char*)d_ws;
    size_t off = 0;
    auto alloc = [&](size_t bytes) -> void* {
        void* p = wsb + off;
        off = (off + bytes + 255) & ~(size_t)255;
        return p;
    };
    ushort_t* h2   = (ushort_t*)alloc((size_t)N * HC * 2);
    ushort_t* Wf   = (ushort_t*)alloc((size_t)IN_DIM * HC * 2);
    float*    a_src= (float*)alloc((size_t)N * HEADS * 4);
    float*    a_dst= (float*)alloc((size_t)N * HEADS * 4);
    int*      deg  = (int*)alloc((size_t)N * 4);
    ushort_t* ell  = (ushort_t*)alloc((size_t)N * ELL_CAP * 2);

    const int edge_blocks = (E / 4 + 255) / 256;

    hipMemsetAsync(deg, 0, (size_t)N * 4, stream);
    hipLaunchKernelGGL(prep_build, dim3(16 + edge_blocks), dim3(256), 0, stream,
                       W, Wf, esrc, edst, deg, ell, E);
    hipLaunchKernelGGL(gemm_mfma, dim3((N + 127) / 128), dim3(256), 0, stream,
                       x, Wf, att_src, att_dst, h2, a_src, a_dst, N);
    hipLaunchKernelGGL(aggregate, dim3((N + 3) / 4), dim3(256), 0, stream,
                       h2, a_src, a_dst, deg, ell, bias, out, N);
}